// Round 1
// 76.495 us; speedup vs baseline: 1.1309x; 1.1309x over previous
//
#include <hip/hip_runtime.h>
#include <math.h>

// R5: latency/occupancy attack.
// rocprof R4: VALUBusy 3.7%, Occupancy 2.5% -> 64 blocks x 1 wave/SIMD on 64 of
// 256 CUs; ~85% stall on active SIMDs. Serial Schur's ds_bpermute (~120cyc,
// LDS-domain) on the critical path; head/tail LDS reads un-hidden at 1 wave/SIMD.
// Changes:
//  1. NTH 256 -> 1024 (16 waves, 4/SIMD latency hiding).
//  2. Unified banded matvec: normalized columns stored TRANSPOSED colDT[entry][col]
//     stride 129 (129 % 32 == 1 -> conflict-free for Schur writes AND b128 coeff
//     reads). 256 row-quads x 4 j-quarters; 4-row sliding us-window keeps LDS
//     traffic at 1 ds_read_b128 per 4 row-contributions.
//  3. Per-jq partial float4 planes (no atomics), fused single-pass scan + output.
//  4. Schur lane-shift via DPP wave_shl:1 (VALU latency) with runtime probe and
//     ds_bpermute fallback (correctness-safe if DPP semantics differ).
//  5. Wave 0 skips staging -> Schur starts immediately; staging hides under it.

#define TM1 1023
#define NTH 1024
#define K0  128
#define CSTRIDE 129

__device__ __forceinline__ float bperm(int a, float v) {
    return __int_as_float(__builtin_amdgcn_ds_bpermute(a, __float_as_int(v)));
}
__device__ __forceinline__ float rdlane(float v, int s) {
    return __int_as_float(__builtin_amdgcn_readlane(__float_as_int(v), s));
}
__device__ __forceinline__ float dpp_shl1(float v) {
    // WAVE_SHL1 = 0x130: dst[l] = src[l+1], lane 63 -> 0 (bound_ctrl).
    return __int_as_float(__builtin_amdgcn_update_dpp(
        0, __float_as_int(v), 0x130, 0xF, 0xF, true));
}
// mod-4 deinterleaved slot for us storage: plane (k&3), index (k>>2).
// With per-lane k stride 4 (quad rows), plane is wave-uniform and index is
// stride-1 -> conflict-free b128 reads.
__device__ __forceinline__ int uslot(int k) { return ((k & 3) << 8) | (k >> 2); }

__device__ __forceinline__ float4 ldus(const float4* us4s, int k) {
    int kc = (k < 0) ? 0 : k;
    float4 v = us4s[uslot(kc)];
    if (k < 0) { v.x = 0.f; v.y = 0.f; v.z = 0.f; }
    return v;
}

// One row-quad (rows B..B+3), j-range [32*jq, 32*jq+32).
// MIXED (rows 0..255): coefficient = colDT[j][k] for k<128 else Lc[j];
// pure tail (rows >=256): coefficient = Lc[j] always (k = row-j >= 129).
template<bool MIXED>
__device__ __forceinline__ void conv_quad(
    const float4* us4s, const float* colDT, float lca, float lcb,
    int B, int jq, int quad, float4* ypx4, float4* ypy4, float4* ypz4)
{
    const int   j0   = jq << 5;
    const float lsel = (jq < 2) ? lca : lcb;   // wave-uniform half select

    float4 q0 = MIXED ? ldus(us4s, B + 0 - j0) : us4s[uslot(B + 0 - j0)];
    float4 q1 = MIXED ? ldus(us4s, B + 1 - j0) : us4s[uslot(B + 1 - j0)];
    float4 q2 = MIXED ? ldus(us4s, B + 2 - j0) : us4s[uslot(B + 2 - j0)];
    float4 q3 = MIXED ? ldus(us4s, B + 3 - j0) : us4s[uslot(B + 3 - j0)];

    float a0x=0,a0y=0,a0z=0, a1x=0,a1y=0,a1z=0;
    float a2x=0,a2y=0,a2z=0, a3x=0,a3y=0,a3z=0;

    #pragma unroll 8
    for (int jj = 0; jj < 32; ++jj) {
        const int j = j0 + jj;
        float lcj = rdlane(lsel, j & 63);
        float c0 = lcj, c1 = lcj, c2 = lcj, c3 = lcj;
        if (MIXED) {
            int p = B - j;
            // dword addr = 129*j + (B-j) = 128*j + B : 16B-aligned for every j,
            // lane-consecutive (B stride 4) -> conflict-free b128.
            float4 h = *reinterpret_cast<const float4*>(&colDT[(j << 7) + B]);
            // k_i = p+i. k_i in [0,128): head coeff; k_i >= 128: tail coeff;
            // k_i < 0: h is garbage-but-finite, us window is 0 -> contributes 0.
            c0 = (p + 0 < 128) ? h.x : lcj;
            c1 = (p + 1 < 128) ? h.y : lcj;
            c2 = (p + 2 < 128) ? h.z : lcj;
            c3 = (p + 3 < 128) ? h.w : lcj;
        }
        a0x = fmaf(c0, q0.x, a0x); a0y = fmaf(c0, q0.y, a0y); a0z = fmaf(c0, q0.z, a0z);
        a1x = fmaf(c1, q1.x, a1x); a1y = fmaf(c1, q1.y, a1y); a1z = fmaf(c1, q1.z, a1z);
        a2x = fmaf(c2, q2.x, a2x); a2y = fmaf(c2, q2.y, a2y); a2z = fmaf(c2, q2.z, a2z);
        a3x = fmaf(c3, q3.x, a3x); a3y = fmaf(c3, q3.y, a3y); a3z = fmaf(c3, q3.z, a3z);
        int xi = B - j - 1;                      // slide window down by one
        float4 nv = MIXED ? ldus(us4s, xi) : us4s[uslot(xi)];
        q3 = q2; q2 = q1; q1 = q0; q0 = nv;
    }
    ypx4[(jq << 8) + quad] = make_float4(a0x, a1x, a2x, a3x);
    ypy4[(jq << 8) + quad] = make_float4(a0y, a1y, a2y, a3y);
    ypz4[(jq << 8) + quad] = make_float4(a0z, a1z, a2z, a3z);
}

__global__ __launch_bounds__(NTH, 1)
void fbm_schur_kernel(const float* __restrict__ alpha,
                      const float* __restrict__ tau,
                      const float* __restrict__ diffusion,
                      const float* __restrict__ du,
                      float* __restrict__ out)
{
    const int b   = blockIdx.x;
    const int tid = threadIdx.x;
    const int w   = tid >> 6;
    const int l   = tid & 63;

    __shared__ float  colDT[K0 * CSTRIDE];  // normalized cols, transposed, 64.5 KB
    __shared__ float4 us4[1024];            // du*sd, plane-permuted, 16 KB
    __shared__ float4 ypx4[4 * 256];        // per-jq partials, 16 KB each
    __shared__ float4 ypy4[4 * 256];
    __shared__ float4 ypz4[4 * 256];
    __shared__ float  Lc[128];              // converged normalized column
    __shared__ float  wtot[48];

    const float sd = sqrtf(diffusion[b]);
    const float* dub = du + (size_t)b * (TM1 * 3);

    if (w > 0) {
        // ---- staging by waves 1..15 (wave 0 goes straight to Schur) ----
        for (int e = tid - 64; e < TM1 * 3; e += (NTH - 64)) {
            int k = e / 3, d = e - 3 * k;
            ((float*)&us4[uslot(k)])[d] = dub[e] * sd;
        }
        for (int i = tid - 64; i < K0; i += (NTH - 64))
            colDT[i * CSTRIDE + 128] = 0.f;             // zero pads (NaN guard)
        if (tid == 64) us4[uslot(1023)] = make_float4(0.f, 0.f, 0.f, 0.f);
    } else {
        // ---- generator init (f64 covariance, cast f32) ----
        const double a  = (double)alpha[b];
        const double tb = (double)tau[b];
        auto cov = [&](int k) -> float {
            if (k == 0) return 1.0f;
            double dk = (double)k;
            double ck = 0.5 * (pow(dk + 1.0, a) + pow(dk - 1.0, a) - 2.0 * pow(dk, a));
            if (dk >= tb) ck *= exp(tb - dk);
            return (float)ck;
        };
        float g1a = cov(l);
        float g1b = cov(l + 64);
        float g2a = (l == 0) ? 0.f : g1a;
        float g2b = g1b;

        // Probe DPP wave_shl:1 direction; fall back to bpermute if it does not
        // deliver dst[l] = src[l+1] on this HW/compiler.
        int probe = __builtin_amdgcn_update_dpp(0, l + 100, 0x130, 0xF, 0xF, true);
        const bool dpp_ok = (__builtin_amdgcn_readlane(probe, 5) == 106);
        const int addr_up = ((l + 1) & 63) << 2;

        // ---- serial Schur: K0 steps (R3-verified recursion), normalized
        //      transposed column writes (stride 129 -> conflict-free) ----
#define SCHUR_LOOP(SHA, SHB)                                               \
        for (int k = 0; k < K0; ++k) {                                     \
            float den  = rdlane(g1a, 0);                                   \
            float sc   = __frsqrt_rn(den);                                 \
            colDT[l * CSTRIDE + k]        = g1a * sc;                      \
            colDT[(64 + l) * CSTRIDE + k] = g1b * sc;                      \
            float num  = rdlane(g2a, 1);                                   \
            float r    = num * __builtin_amdgcn_rcpf(den);                 \
            float wrap = rdlane(g2b, 0);                                   \
            float g2pa = (SHA);                                            \
            float g2pb = (SHB);                                            \
            if (l == 63) { g2pa = wrap; g2pb = 0.f; }                      \
            float n1a = fmaf(-r, g2pa, g1a);                               \
            float n1b = fmaf(-r, g2pb, g1b);                               \
            g2a = fmaf(-r, g1a, g2pa);                                     \
            g2b = fmaf(-r, g1b, g2pb);                                     \
            g1a = n1a; g1b = n1b;                                          \
        }
        if (dpp_ok) {
            SCHUR_LOOP(dpp_shl1(g2a), dpp_shl1(g2b))
        } else {
            SCHUR_LOOP(bperm(addr_up, g2a), bperm(addr_up, g2b))
        }
#undef SCHUR_LOOP
        float sc = __frsqrt_rn(rdlane(g1a, 0));
        Lc[l]      = g1a * sc;
        Lc[64 + l] = g1b * sc;
    }
    __syncthreads();

    // ---- unified banded matvec: 256 row-quads x 4 j-quarters ----
    {
        float lca = Lc[l], lcb = Lc[64 + l];
        const int jq   = w & 3;              // j-quarter
        const int rb   = w >> 2;             // row block of 256
        const int quad = (rb << 6) + l;      // 0..255
        const int B    = quad << 2;          // rows B..B+3
        if (rb == 0)
            conv_quad<true >(us4, colDT, lca, lcb, B, jq, quad, ypx4, ypy4, ypz4);
        else
            conv_quad<false>(us4, colDT, lca, lcb, B, jq, quad, ypx4, ypy4, ypz4);
    }
    __syncthreads();

    // ---- fused: sum jq planes + 16-wave scan + output ----
    const int i = tid;
    float sx = 0.f, sy = 0.f, sz = 0.f;
    if (i < TM1) {
        const float* px = (const float*)ypx4;
        const float* py = (const float*)ypy4;
        const float* pz = (const float*)ypz4;
        sx = px[i] + px[1024 + i] + px[2048 + i] + px[3072 + i];
        sy = py[i] + py[1024 + i] + py[2048 + i] + py[3072 + i];
        sz = pz[i] + pz[1024 + i] + pz[2048 + i] + pz[3072 + i];
    }
    #pragma unroll
    for (int off = 1; off < 64; off <<= 1) {
        float tx = __shfl_up(sx, off);
        float ty = __shfl_up(sy, off);
        float tz = __shfl_up(sz, off);
        if (l >= off) { sx += tx; sy += ty; sz += tz; }
    }
    if (l == 63) { wtot[w * 3 + 0] = sx; wtot[w * 3 + 1] = sy; wtot[w * 3 + 2] = sz; }
    __syncthreads();

    float ox = 0.f, oy = 0.f, oz = 0.f;
    for (int q = 0; q < w; ++q) {
        ox += wtot[q * 3 + 0]; oy += wtot[q * 3 + 1]; oz += wtot[q * 3 + 2];
    }
    float* outb = out + (size_t)b * (TM1 + 1) * 3;
    if (i < TM1) {
        outb[(i + 1) * 3 + 0] = sx + ox;
        outb[(i + 1) * 3 + 1] = sy + oy;
        outb[(i + 1) * 3 + 2] = sz + oz;
    }
    if (tid == 0) { outb[0] = 0.f; outb[1] = 0.f; outb[2] = 0.f; }
}

extern "C" void kernel_launch(void* const* d_in, const int* in_sizes, int n_in,
                              void* d_out, int out_size, void* d_ws, size_t ws_size,
                              hipStream_t stream)
{
    const float* alpha     = (const float*)d_in[0];
    const float* tau       = (const float*)d_in[1];
    const float* diffusion = (const float*)d_in[2];
    const float* du        = (const float*)d_in[3];
    float* out = (float*)d_out;
    const int BS = in_sizes[0];

    fbm_schur_kernel<<<dim3(BS), dim3(NTH), 0, stream>>>(
        alpha, tau, diffusion, du, out);
}

// Round 2
// 76.387 us; speedup vs baseline: 1.1325x; 1.0014x over previous
//
#include <hip/hip_runtime.h>
#include <math.h>

// R6: cycle cuts under throttled clocks.
// R5 evidence: kernel fell below the 40us harness fills (top-5 all
// fillBufferAligned @82% HBM). Inferred kernel ~32-37us vs ~6us @2.4GHz cycle
// model -> DVFS-throttled, cycle-bound. Cuts:
//  1. Scalarized Schur denominator: den' = den - r*num (bit-exact same fma as
//     lane0's update) -> rcp/rsqrt computed one step AHEAD, off critical path.
//  2. Runtime K = min(128, ceil(tau)+48): r ~ e^{-(k-tau)} < 1e-16 beyond.
//     Head masks -> unsigned compares vs K (negatives/uninit cols select Lc).
//  3. Init pow-sharing: 2 f64 pows/lane instead of 6 (neighbor shuffles;
//     lane0 computes p[128] in its dead p[0] slot).
//  4. DPP wave scan (row_shr1/2/4/8 + row_bcast15/31), runtime-probed with
//     shfl_up fallback.

#define TM1 1023
#define NTH 1024
#define K0  128
#define CSTRIDE 129

__device__ __forceinline__ float bperm(int a, float v) {
    return __int_as_float(__builtin_amdgcn_ds_bpermute(a, __float_as_int(v)));
}
__device__ __forceinline__ float rdlane(float v, int s) {
    return __int_as_float(__builtin_amdgcn_readlane(__float_as_int(v), s));
}
__device__ __forceinline__ float dpp_shl1(float v) {
    // WAVE_SHL1 = 0x130: dst[l] = src[l+1] (probed; bpermute fallback if not).
    return __int_as_float(__builtin_amdgcn_update_dpp(
        0, __float_as_int(v), 0x130, 0xF, 0xF, true));
}
template<int CTRL, int RM, bool BC>
__device__ __forceinline__ float dppadd(float s) {
    float t = __int_as_float(__builtin_amdgcn_update_dpp(
        0, __float_as_int(s), CTRL, RM, 0xF, BC));
    return s + t;
}
// wave64 inclusive add-scan via DPP (classic GCN idiom), probed at runtime
__device__ __forceinline__ float dpp_scan(float s) {
    s = dppadd<0x111, 0xF, true >(s);   // row_shr:1
    s = dppadd<0x112, 0xF, true >(s);   // row_shr:2
    s = dppadd<0x114, 0xF, true >(s);   // row_shr:4
    s = dppadd<0x118, 0xF, true >(s);   // row_shr:8
    s = dppadd<0x142, 0xA, false>(s);   // row_bcast:15 -> rows 1,3
    s = dppadd<0x143, 0xC, false>(s);   // row_bcast:31 -> rows 2,3
    return s;
}
// mod-4 deinterleaved slot for us storage: plane (k&3), index (k>>2)
__device__ __forceinline__ int uslot(int k) { return ((k & 3) << 8) | (k >> 2); }

__device__ __forceinline__ float4 ldus(const float4* us4s, int k) {
    int kc = (k < 0) ? 0 : k;
    float4 v = us4s[uslot(kc)];
    if (k < 0) { v.x = 0.f; v.y = 0.f; v.z = 0.f; }
    return v;
}

// One row-quad (rows B..B+3), j-range [32*jq, 32*jq+32).
// MIXED (rows 0..255): coeff = colDT[j][k] for k in [0,K) else Lc[j]
// (unsigned compare: k<0 and k in [K,128) both select finite Lc; the k<0
// case additionally has a zeroed us window so it contributes 0).
// Pure tail (rows >=256): coeff = Lc[j] always (k = row-j >= 129 > K).
template<bool MIXED>
__device__ __forceinline__ void conv_quad(
    const float4* us4s, const float* colDT, float lca, float lcb,
    int B, int jq, int quad, int K, float4* ypx4, float4* ypy4, float4* ypz4)
{
    const int      j0   = jq << 5;
    const float    lsel = (jq < 2) ? lca : lcb;   // wave-uniform half select
    const unsigned Ku   = (unsigned)K;

    float4 q0 = MIXED ? ldus(us4s, B + 0 - j0) : us4s[uslot(B + 0 - j0)];
    float4 q1 = MIXED ? ldus(us4s, B + 1 - j0) : us4s[uslot(B + 1 - j0)];
    float4 q2 = MIXED ? ldus(us4s, B + 2 - j0) : us4s[uslot(B + 2 - j0)];
    float4 q3 = MIXED ? ldus(us4s, B + 3 - j0) : us4s[uslot(B + 3 - j0)];

    float a0x=0,a0y=0,a0z=0, a1x=0,a1y=0,a1z=0;
    float a2x=0,a2y=0,a2z=0, a3x=0,a3y=0,a3z=0;

    #pragma unroll 8
    for (int jj = 0; jj < 32; ++jj) {
        const int j = j0 + jj;
        float lcj = rdlane(lsel, j & 63);
        float c0 = lcj, c1 = lcj, c2 = lcj, c3 = lcj;
        if (MIXED) {
            int p = B - j;
            // dword addr = 129*j + (B-j) = 128*j + B : 16B-aligned every j,
            // lane-consecutive (B stride 4) -> conflict-free b128.
            float4 h = *reinterpret_cast<const float4*>(&colDT[(j << 7) + B]);
            c0 = ((unsigned)(p + 0) < Ku) ? h.x : lcj;
            c1 = ((unsigned)(p + 1) < Ku) ? h.y : lcj;
            c2 = ((unsigned)(p + 2) < Ku) ? h.z : lcj;
            c3 = ((unsigned)(p + 3) < Ku) ? h.w : lcj;
        }
        a0x = fmaf(c0, q0.x, a0x); a0y = fmaf(c0, q0.y, a0y); a0z = fmaf(c0, q0.z, a0z);
        a1x = fmaf(c1, q1.x, a1x); a1y = fmaf(c1, q1.y, a1y); a1z = fmaf(c1, q1.z, a1z);
        a2x = fmaf(c2, q2.x, a2x); a2y = fmaf(c2, q2.y, a2y); a2z = fmaf(c2, q2.z, a2z);
        a3x = fmaf(c3, q3.x, a3x); a3y = fmaf(c3, q3.y, a3y); a3z = fmaf(c3, q3.z, a3z);
        int xi = B - j - 1;                      // slide window down by one
        float4 nv = MIXED ? ldus(us4s, xi) : us4s[uslot(xi)];
        q3 = q2; q2 = q1; q1 = q0; q0 = nv;
    }
    ypx4[(jq << 8) + quad] = make_float4(a0x, a1x, a2x, a3x);
    ypy4[(jq << 8) + quad] = make_float4(a0y, a1y, a2y, a3y);
    ypz4[(jq << 8) + quad] = make_float4(a0z, a1z, a2z, a3z);
}

__global__ __launch_bounds__(NTH, 1)
void fbm_schur_kernel(const float* __restrict__ alpha,
                      const float* __restrict__ tau,
                      const float* __restrict__ diffusion,
                      const float* __restrict__ du,
                      float* __restrict__ out)
{
    const int b   = blockIdx.x;
    const int tid = threadIdx.x;
    const int w   = tid >> 6;
    const int l   = tid & 63;

    __shared__ float  colDT[K0 * CSTRIDE];  // normalized cols, transposed, 64.5 KB
    __shared__ float4 us4[1024];            // du*sd, plane-permuted, 16 KB
    __shared__ float4 ypx4[4 * 256];        // per-jq partials, 16 KB each
    __shared__ float4 ypy4[4 * 256];
    __shared__ float4 ypz4[4 * 256];
    __shared__ float  Lc[128];              // converged normalized column
    __shared__ float  wtot[48];

    const float sd = sqrtf(diffusion[b]);
    const float tv = tau[b];
    const int   K  = min(K0, (int)ceilf(tv) + 48);   // r ~ e^{-(k-tau)} < 1e-16 beyond
    const float* dub = du + (size_t)b * (TM1 * 3);

    if (w > 0) {
        // ---- staging by waves 1..15 (wave 0 goes straight to Schur) ----
        for (int e = tid - 64; e < TM1 * 3; e += (NTH - 64)) {
            int k = e / 3, d = e - 3 * k;
            ((float*)&us4[uslot(k)])[d] = dub[e] * sd;
        }
        for (int i = tid - 64; i < K0; i += (NTH - 64))
            colDT[i * CSTRIDE + 128] = 0.f;             // zero pads (NaN guard)
        if (tid == 64) us4[uslot(1023)] = make_float4(0.f, 0.f, 0.f, 0.f);
    } else {
        // ---- generator init: p[k] = k^a shared across lanes (2 pows/lane) ----
        const double a  = (double)alpha[b];
        const double tb = (double)tv;
        double pa = pow((double)(l == 0 ? 128 : l), a);  // lane0 holds p[128]
        double pb = pow((double)(l + 64), a);
        double pam1 = __shfl_up(pa, 1);                  // p[l-1]
        double pap1 = __shfl_down(pa, 1);                // p[l+1]
        double pbm1 = __shfl_up(pb, 1);                  // p[l+63]
        double pbp1 = __shfl_down(pb, 1);                // p[l+65]
        double p63  = __shfl(pa, 63);
        double p64  = __shfl(pb, 0);
        double p128 = __shfl(pa, 0);
        if (l == 1)  pam1 = 0.0;                         // p[0] = 0
        if (l == 63) pap1 = p64;
        if (l == 0)  pbm1 = p63;
        if (l == 63) pbp1 = p128;
        auto covk = [&](int k, double pm, double p0, double pp) -> float {
            if (k == 0) return 1.0f;
            double ck = 0.5 * (pp + pm - 2.0 * p0);
            double dk = (double)k;
            if (dk >= tb) ck *= exp(tb - dk);
            return (float)ck;
        };
        float g1a = covk(l,      pam1, (l == 0 ? 0.0 : pa), pap1);
        float g1b = covk(l + 64, pbm1, pb,                  pbp1);
        float g2a = (l == 0) ? 0.f : g1a;
        float g2b = g1b;

        // Probe DPP wave_shl:1 direction; fall back to bpermute if wrong.
        int probe = __builtin_amdgcn_update_dpp(0, l + 100, 0x130, 0xF, 0xF, true);
        const bool dpp_ok = (__builtin_amdgcn_readlane(probe, 5) == 106);
        const int addr_up = ((l + 1) & 63) << 2;

        // ---- serial Schur, K steps. den recursion is scalar-uniform:
        //      den' = fma(-r, num, den) == lane0's vector update (bit-exact),
        //      so rcp/rsqrt are one step ahead, off the critical path. ----
        float den = 1.0f, rcpden = 1.0f, sc = 1.0f;     // den_0 = cov(0) = 1
#define SCHUR_LOOP(SHA, SHB)                                               \
        for (int k = 0; k < K; ++k) {                                      \
            colDT[l * CSTRIDE + k]        = g1a * sc;                      \
            colDT[(64 + l) * CSTRIDE + k] = g1b * sc;                      \
            float num  = rdlane(g2a, 1);                                   \
            float r    = num * rcpden;                                     \
            float wrap = rdlane(g2b, 0);                                   \
            float g2pa = (SHA);                                            \
            float g2pb = (SHB);                                            \
            if (l == 63) { g2pa = wrap; g2pb = 0.f; }                      \
            float n1a = fmaf(-r, g2pa, g1a);                               \
            float n1b = fmaf(-r, g2pb, g1b);                               \
            g2a = fmaf(-r, g1a, g2pa);                                     \
            g2b = fmaf(-r, g1b, g2pb);                                     \
            g1a = n1a; g1b = n1b;                                          \
            den    = fmaf(-r, num, den);                                   \
            rcpden = __builtin_amdgcn_rcpf(den);                           \
            sc     = __frsqrt_rn(den);                                     \
        }
        if (dpp_ok) {
            SCHUR_LOOP(dpp_shl1(g2a), dpp_shl1(g2b))
        } else {
            SCHUR_LOOP(bperm(addr_up, g2a), bperm(addr_up, g2b))
        }
#undef SCHUR_LOOP
        Lc[l]      = g1a * sc;      // sc == rsqrt(den_K)
        Lc[64 + l] = g1b * sc;
    }
    __syncthreads();

    // ---- unified banded matvec: 256 row-quads x 4 j-quarters ----
    {
        float lca = Lc[l], lcb = Lc[64 + l];
        const int jq   = w & 3;              // j-quarter
        const int rb   = w >> 2;             // row block of 256
        const int quad = (rb << 6) + l;      // 0..255
        const int B    = quad << 2;          // rows B..B+3
        if (rb == 0)
            conv_quad<true >(us4, colDT, lca, lcb, B, jq, quad, K, ypx4, ypy4, ypz4);
        else
            conv_quad<false>(us4, colDT, lca, lcb, B, jq, quad, K, ypx4, ypy4, ypz4);
    }
    __syncthreads();

    // ---- fused: sum jq planes + 16-wave scan + output ----
    const int i = tid;
    float sx = 0.f, sy = 0.f, sz = 0.f;
    if (i < TM1) {
        const float* px = (const float*)ypx4;
        const float* py = (const float*)ypy4;
        const float* pz = (const float*)ypz4;
        sx = px[i] + px[1024 + i] + px[2048 + i] + px[3072 + i];
        sy = py[i] + py[1024 + i] + py[2048 + i] + py[3072 + i];
        sz = pz[i] + pz[1024 + i] + pz[2048 + i] + pz[3072 + i];
    }
    // DPP scan (probed) with shfl_up fallback
    {
        float pv = dpp_scan(1.0f);
        const bool scan_ok = (rdlane(pv, 63) == 64.0f) && (rdlane(pv, 21) == 22.0f);
        if (scan_ok) {
            sx = dpp_scan(sx); sy = dpp_scan(sy); sz = dpp_scan(sz);
        } else {
            #pragma unroll
            for (int off = 1; off < 64; off <<= 1) {
                float tx = __shfl_up(sx, off);
                float ty = __shfl_up(sy, off);
                float tz = __shfl_up(sz, off);
                if (l >= off) { sx += tx; sy += ty; sz += tz; }
            }
        }
    }
    if (l == 63) { wtot[w * 3 + 0] = sx; wtot[w * 3 + 1] = sy; wtot[w * 3 + 2] = sz; }
    __syncthreads();

    float ox = 0.f, oy = 0.f, oz = 0.f;
    for (int q = 0; q < w; ++q) {
        ox += wtot[q * 3 + 0]; oy += wtot[q * 3 + 1]; oz += wtot[q * 3 + 2];
    }
    float* outb = out + (size_t)b * (TM1 + 1) * 3;
    if (i < TM1) {
        outb[(i + 1) * 3 + 0] = sx + ox;
        outb[(i + 1) * 3 + 1] = sy + oy;
        outb[(i + 1) * 3 + 2] = sz + oz;
    }
    if (tid == 0) { outb[0] = 0.f; outb[1] = 0.f; outb[2] = 0.f; }
}

extern "C" void kernel_launch(void* const* d_in, const int* in_sizes, int n_in,
                              void* d_out, int out_size, void* d_ws, size_t ws_size,
                              hipStream_t stream)
{
    const float* alpha     = (const float*)d_in[0];
    const float* tau       = (const float*)d_in[1];
    const float* diffusion = (const float*)d_in[2];
    const float* du        = (const float*)d_in[3];
    float* out = (float*)d_out;
    const int BS = in_sizes[0];

    fbm_schur_kernel<<<dim3(BS), dim3(NTH), 0, stream>>>(
        alpha, tau, diffusion, du, out);
}